// Round 8
// baseline (172.077 us; speedup 1.0000x reference)
//
#include <hip/hip_runtime.h>
#include <hip/hip_bf16.h>

#define NQ   8192
#define NKEY 8192
#define DH   128

#define BQ   128      // queries per block (4 waves x 32 queries)
#define BK   64       // keys per tile
// LDS 32768 B total -> 4 blocks/CU resident (16 waves/CU):
//   [0,16384)      K fp16 tile (single buffer): 64 rows x 256B, chunk c at c^(r&15)
//   [16384,32768)  Vt bf16 tile (single buffer): 128 n-rows x 128B, chunk c at c^(n&7)
// Vt global is key-permuted by rho = swap(bit2,bit3) within each 32-key group,
// which makes PV B-fragments = sequential p[0..7]/p[8..15] (no lane exchange).
// Pipelining via counted vmcnt: K(t+1) staged right after QK^T(t) frees Kbuf,
// V(t+1) staged after PV(t) frees Vbuf; vmcnt never drained to 0 mid-loop.
// Grid = 64 qb x KS=16 = 1024 blocks = exactly 4/CU (perfect packing).
//
// Occupancy control (measured law, R0-R6): __launch_bounds__(256,N) on this
// toolchain yields EXACTLY N blocks/CU resident (full 512/N-reg allocation
// granule) and caps usable VGPRs at 256/N -- the two are coupled, so it can
// never give 4 blocks/CU spill-free. amdgpu_waves_per_eu(4,8) decouples them:
// LLVM budget = 512/4 = 128 VGPRs (body fits: 84-128), granule 128 -> 4
// waves/SIMD -> 4 blocks/CU by both VGPR and LDS.
#define VBUF 16384
#define LOG2E 1.44269504088896340736f

typedef __attribute__((ext_vector_type(8)))  short    short8;
typedef __attribute__((ext_vector_type(4)))  short    short4v;
typedef _Float16 half8 __attribute__((ext_vector_type(8)));
typedef __attribute__((ext_vector_type(16))) float    f32x16;
typedef __attribute__((ext_vector_type(4)))  float    float4v;

union BFU { __hip_bfloat16 b; unsigned short u; };
__device__ __forceinline__ unsigned short f2bf(float x) { BFU u; u.b = __float2bfloat16(x); return u.u; }

// ---------------- pre-pass: K -> fp16 (RNE), V -> Vt (bf16 transpose, key bit2<->3 swap) ----
__global__ void prep(const float* __restrict__ K, const float* __restrict__ V,
                     _Float16* __restrict__ Kh, unsigned short* __restrict__ Vt) {
    __shared__ __attribute__((aligned(16))) unsigned short tile[64 * 72];
    int b = blockIdx.x;
    int t = threadIdx.x;
    if (b < 512) {                        // K fp16: 1M elements, 8 per thread
        int idx = (b * 256 + t) * 8;
        float4v x0 = *(const float4v*)(K + idx);
        float4v x1 = *(const float4v*)(K + idx + 4);
        half8 o;
#pragma unroll
        for (int j = 0; j < 4; ++j) { o[j] = (_Float16)x0[j]; o[4 + j] = (_Float16)x1[j]; }
        *(half8*)(Kh + idx) = o;
    } else {                              // V transpose: 64(m) x 64(n) tiles
        int tv = b - 512;
        int m0 = (tv >> 1) * 64, n0 = (tv & 1) * 64;
#pragma unroll
        for (int it = 0; it < 4; ++it) {
            int id = t + it * 256;
            int mm = id >> 4, nn0 = (id & 15) * 4;
            // rho: swap bits 2 and 3 of the key index (involution, within-16)
            int mmP = (mm & ~12) | ((mm & 4) << 1) | ((mm & 8) >> 1);
            float4v x = *(const float4v*)(V + (size_t)(m0 + mm) * DH + n0 + nn0);
#pragma unroll
            for (int j = 0; j < 4; ++j)
                tile[(nn0 + j) * 72 + mmP] = f2bf(x[j]);
        }
        __syncthreads();
        int nn = t >> 2, ch = t & 3;
        *(short8*)(Vt + (size_t)(n0 + nn) * NKEY + m0 + ch * 16)     = *(const short8*)&tile[nn * 72 + ch * 16];
        *(short8*)(Vt + (size_t)(n0 + nn) * NKEY + m0 + ch * 16 + 8) = *(const short8*)&tile[nn * 72 + ch * 16 + 8];
    }
}

// ------- forward: S^T = K*(Q*log2e)^T fp16, p = 2^S (no max), O^T = Vtp*P^T bf16 -------
__global__ void __launch_bounds__(256) __attribute__((amdgpu_waves_per_eu(4, 8)))
attn_fwd(const float* __restrict__ Q,
         const _Float16* __restrict__ Kh,
         const unsigned short* __restrict__ Vt,
         unsigned short* __restrict__ Opart, float* __restrict__ lpart,
         int KS) {
    __shared__ __attribute__((aligned(16))) char sbuf[32768];

    const int tid  = threadIdx.x;
    const int lane = tid & 63;
    const int w    = tid >> 6;
    const int l31  = lane & 31;
    const int h    = lane >> 5;

    const int s  = blockIdx.x % KS;
    const int qb = blockIdx.x / KS;
    const int mlen   = NKEY / KS;
    const int kbase  = s * mlen;
    const int ntiles = mlen / BK;          // 8 at KS=16

    // ---- staging maps: per wave 4 K-chunks + 4 V-chunks of 16B
    const char* gbK[4]; int ldsK[4];
    const char* gbV[4]; int ldsV[4];
#pragma unroll
    for (int i = 0; i < 4; ++i) {
        int L = w * 256 + i * 64 + lane;            // linear chunk id, 0..1023
        int r  = L >> 4, cgk = (L & 15) ^ (r & 15); // K: row r (256B), swizzled chunk
        gbK[i]  = (const char*)Kh + r * 256 + cgk * 16;
        ldsK[i] = (w * 256 + i * 64) * 16;          // wave-uniform; HW adds lane*16
        int n  = L >> 3, cgv = (L & 7) ^ (n & 7);   // V: n-row (128B), swizzled chunk
        gbV[i]  = (const char*)Vt + (size_t)n * (NKEY * 2) + cgv * 16;
        ldsV[i] = VBUF + (w * 256 + i * 64) * 16;
    }

    auto stageK = [&](int t) {                      // 4 loads -> K buffer
        int kb = kbase + t * BK;
#pragma unroll
        for (int i = 0; i < 4; ++i)
            __builtin_amdgcn_global_load_lds(
                (const __attribute__((address_space(1))) unsigned int*)(gbK[i] + (size_t)kb * 256),
                (__attribute__((address_space(3))) unsigned int*)(sbuf + ldsK[i]),
                16, 0, 0);
    };
    auto stageV = [&](int t) {                      // 4 loads -> V buffer
        int kb = kbase + t * BK;
#pragma unroll
        for (int i = 0; i < 4; ++i)
            __builtin_amdgcn_global_load_lds(
                (const __attribute__((address_space(1))) unsigned int*)(gbV[i] + (size_t)kb * 2),
                (__attribute__((address_space(3))) unsigned int*)(sbuf + ldsV[i]),
                16, 0, 0);
    };

    // prologue staging first so Q-load latency overlaps it
    stageK(0);
    stageV(0);

    // ---- Q fragments fp16, scaled by log2e; B-layout: lane=query, k=c*16+h*8+j
    const int qrow = qb * BQ + w * 32 + l31;
    half8 qf[8];
#pragma unroll
    for (int c = 0; c < 8; ++c) {
        const float* qp = Q + (size_t)qrow * DH + c * 16 + h * 8;
        float4v x0 = *(const float4v*)qp;
        float4v x1 = *(const float4v*)(qp + 4);
#pragma unroll
        for (int i = 0; i < 4; ++i) {
            qf[c][i]     = (_Float16)(x0[i] * LOG2E);
            qf[c][4 + i] = (_Float16)(x1[i] * LOG2E);
        }
    }

    // ---- LDS read offsets
    int koff[8];
#pragma unroll
    for (int c = 0; c < 8; ++c)
        koff[c] = l31 * 256 + (((c * 2 + h) ^ (l31 & 15)) << 4);
    int voff[4];
#pragma unroll
    for (int c2 = 0; c2 < 4; ++c2)
        voff[c2] = VBUF + l31 * 128 + (((c2 * 2 + h) ^ (l31 & 7)) << 4);

    float lsum = 0.0f;   // per-half-wave partial; combined once in epilogue
    f32x16 O[4];
#pragma unroll
    for (int ct = 0; ct < 4; ++ct)
#pragma unroll
        for (int r = 0; r < 16; ++r) O[ct][r] = 0.0f;

    __syncthreads();     // full drain: K(0), V(0), Q complete & visible

    for (int t = 0; t < ntiles; ++t) {
        // entry invariant: Kbuf = K(t) ready & visible; V(t) loads retired or in flight(4)
        // ---- QK^T (fp16): two 32-key groups (independent MFMA chains)
        f32x16 S0, S1;
#pragma unroll
        for (int r = 0; r < 16; ++r) { S0[r] = 0.0f; S1[r] = 0.0f; }
#pragma unroll
        for (int c = 0; c < 8; ++c) {
            half8 k0 = *(const half8*)(sbuf + koff[c]);
            half8 k1 = *(const half8*)(sbuf + koff[c] + 8192);
            S0 = __builtin_amdgcn_mfma_f32_32x32x16_f16(k0, qf[c], S0, 0, 0, 0);
            S1 = __builtin_amdgcn_mfma_f32_32x32x16_f16(k1, qf[c], S1, 0, 0, 0);
        }
        // (A) all waves done reading Kbuf -> free for K(t+1)
        asm volatile("s_waitcnt lgkmcnt(0)" ::: "memory");
        __builtin_amdgcn_s_barrier();
        if (t + 1 < ntiles) stageK(t + 1);      // in flight across exp2 + PV

        // ---- exp2 + pack (covers K(t+1) issue latency)
        union PU { unsigned int u[4]; short8 s8; } B0, B1, B2, B3;
        {
            float p0[16]; float ps = 0.0f;
#pragma unroll
            for (int r = 0; r < 16; ++r) { p0[r] = __builtin_amdgcn_exp2f(S0[r]); ps += p0[r]; }
            lsum += ps;
#pragma unroll
            for (int j = 0; j < 4; ++j) {
                B0.u[j] = __builtin_amdgcn_perm(__float_as_uint(p0[2*j+1]), __float_as_uint(p0[2*j]),   0x07060302u);
                B1.u[j] = __builtin_amdgcn_perm(__float_as_uint(p0[2*j+9]), __float_as_uint(p0[2*j+8]), 0x07060302u);
            }
        }
        {
            float p1[16]; float ps = 0.0f;
#pragma unroll
            for (int r = 0; r < 16; ++r) { p1[r] = __builtin_amdgcn_exp2f(S1[r]); ps += p1[r]; }
            lsum += ps;
#pragma unroll
            for (int j = 0; j < 4; ++j) {
                B2.u[j] = __builtin_amdgcn_perm(__float_as_uint(p1[2*j+1]), __float_as_uint(p1[2*j]),   0x07060302u);
                B3.u[j] = __builtin_amdgcn_perm(__float_as_uint(p1[2*j+9]), __float_as_uint(p1[2*j+8]), 0x07060302u);
            }
        }

        // (B) V(t) complete (K(t+1)'s 4 loads stay in flight when present)
        if (t + 1 < ntiles) { asm volatile("s_waitcnt vmcnt(4)" ::: "memory"); }
        else                { asm volatile("s_waitcnt vmcnt(0)" ::: "memory"); }
        __builtin_amdgcn_s_barrier();

        // ---- PV: O^T += Vtp * P^T (bf16)
        {
            short8 va0[4], va1[4];
#pragma unroll
            for (int ct = 0; ct < 4; ++ct) {
                va0[ct] = *(const short8*)(sbuf + voff[0] + ct * 4096);
                va1[ct] = *(const short8*)(sbuf + voff[1] + ct * 4096);
            }
#pragma unroll
            for (int ct = 0; ct < 4; ++ct) {
                O[ct] = __builtin_amdgcn_mfma_f32_32x32x16_bf16(va0[ct], B0.s8, O[ct], 0, 0, 0);
                O[ct] = __builtin_amdgcn_mfma_f32_32x32x16_bf16(va1[ct], B1.s8, O[ct], 0, 0, 0);
            }
        }
        {
            short8 va2[4], va3[4];
#pragma unroll
            for (int ct = 0; ct < 4; ++ct) {
                va2[ct] = *(const short8*)(sbuf + voff[2] + ct * 4096);
                va3[ct] = *(const short8*)(sbuf + voff[3] + ct * 4096);
            }
#pragma unroll
            for (int ct = 0; ct < 4; ++ct) {
                O[ct] = __builtin_amdgcn_mfma_f32_32x32x16_bf16(va2[ct], B2.s8, O[ct], 0, 0, 0);
                O[ct] = __builtin_amdgcn_mfma_f32_32x32x16_bf16(va3[ct], B3.s8, O[ct], 0, 0, 0);
            }
        }

        if (t + 1 < ntiles) {
            // (C) all waves done reading Vbuf -> free for V(t+1)
            asm volatile("s_waitcnt lgkmcnt(0)" ::: "memory");
            __builtin_amdgcn_s_barrier();
            stageV(t + 1);                       // outstanding: K(t+1)4 + V(t+1)4
            // (D) K(t+1) complete (V(t+1) stays in flight) -> entry invariant
            asm volatile("s_waitcnt vmcnt(4)" ::: "memory");
            __builtin_amdgcn_s_barrier();
        }
    }

    // ---- epilogue: combine half-wave lsums, then store O^T C-layout
    lsum += __shfl_xor(lsum, 32, 64);
    {
        unsigned short* Ob = Opart + ((size_t)s * NQ + qrow) * DH;
#pragma unroll
        for (int ct = 0; ct < 4; ++ct)
#pragma unroll
            for (int g = 0; g < 4; ++g) {
                short4v v;
#pragma unroll
                for (int j = 0; j < 4; ++j) v[j] = (short)f2bf(O[ct][4 * g + j]);
                *(short4v*)(Ob + ct * 32 + 8 * g + 4 * h) = v;
            }
        if (h == 0)
            lpart[(size_t)s * NQ + qrow] = lsum;
    }
}

__global__ void attn_combine(const unsigned short* __restrict__ Opart,
                             const float* __restrict__ lpart, float* __restrict__ out, int KS) {
    int idx = blockIdx.x * 256 + threadIdx.x;   // one thread per 4 output cols
    int row = idx >> 5;
    int col = (idx & 31) << 2;
    float den = 0.0f;
    float a0 = 0.0f, a1 = 0.0f, a2 = 0.0f, a3 = 0.0f;
    for (int s2 = 0; s2 < KS; ++s2) {
        den += lpart[(size_t)s2 * NQ + row];
        const unsigned short* op = Opart + ((size_t)s2 * NQ + row) * DH + col;
        uint2 u = *(const uint2*)op;
        a0 += __uint_as_float(u.x << 16);
        a1 += __uint_as_float(u.x & 0xffff0000u);
        a2 += __uint_as_float(u.y << 16);
        a3 += __uint_as_float(u.y & 0xffff0000u);
    }
    float r = 1.0f / den;
    float4v v; v[0] = a0 * r; v[1] = a1 * r; v[2] = a2 * r; v[3] = a3 * r;
    *(float4v*)(out + (size_t)row * DH + col) = v;
}

extern "C" void kernel_launch(void* const* d_in, const int* in_sizes, int n_in,
                              void* d_out, int out_size, void* d_ws, size_t ws_size,
                              hipStream_t stream) {
    const float* Q = (const float*)d_in[0];
    const float* K = (const float*)d_in[1];
    const float* V = (const float*)d_in[2];
    float* out = (float*)d_out;

    const size_t prep_bytes = 2 * (size_t)NKEY * DH * sizeof(unsigned short); // 4 MB
    int KS = 16;   // grid = 64*16 = 1024 blocks -> exactly 4 blocks/CU at 32KiB LDS
    while (KS > 1 &&
           ws_size < prep_bytes + (size_t)KS * ((size_t)NQ * DH * 2 + NQ * 4))
        KS >>= 1;

    _Float16* Kh = (_Float16*)d_ws;
    unsigned short* Vt = (unsigned short*)(Kh + (size_t)NKEY * DH);
    unsigned short* Opart = Vt + (size_t)NKEY * DH;
    float* lpart = (float*)(Opart + (size_t)KS * NQ * DH);

    hipLaunchKernelGGL(prep, dim3(768), dim3(256), 0, stream, K, V, Kh, Vt);
    hipLaunchKernelGGL(attn_fwd, dim3((NQ / BQ) * KS), dim3(256), 0, stream,
                       Q, Kh, Vt, Opart, lpart, KS);
    hipLaunchKernelGGL(attn_combine, dim3((NQ * DH) / 4 / 256), dim3(256), 0, stream,
                       Opart, lpart, out, KS);
}

// Round 9
// 122.670 us; speedup vs baseline: 1.4028x; 1.4028x over previous
//
#include <hip/hip_runtime.h>
#include <hip/hip_bf16.h>

#define NQ   8192
#define NKEY 8192
#define DH   128

#define BQ   256      // queries per block (8 waves x 32 queries)
#define BK   64       // keys per tile
// LDS per buffer (32768 B):
//   [0,16384)      K fp16 tile: 64 rows x 256B, chunk c stored at c^(r&15)
//   [16384,32768)  Vt bf16 tile: 128 n-rows x 128B, chunk c at c^(n&7)
// Vt global is key-permuted by rho = swap(bit2,bit3) within each 32-key group,
// which makes PV B-fragments = sequential p[0..7]/p[8..15] (no lane exchange).
// Grid = (NQ/BQ)*KS = 32*16 = 512 blocks of 512 threads -> exactly 2 blocks/CU
// by LDS (2x64KiB=128<=160), i.e. 16 waves/CU = 4 waves/SIMD.
//
// VGPR law measured R0-R8 (both __launch_bounds__ 2nd arg and
// amdgpu_waves_per_eu): cap = 256/min_waves. Body needs ~128 (O[4] f32x16
// = 64 alone). So min_waves MUST be 2: cap 128, spill-free (R0 compiled
// this body at exactly 128). With 64KiB LDS the runtime residency is
// LDS-capped at 2 blocks/CU regardless -> no conflict with min_waves=2.
#define BUFB 32768
#define LOG2E 1.44269504088896340736f

typedef __attribute__((ext_vector_type(8)))  short    short8;
typedef __attribute__((ext_vector_type(4)))  short    short4v;
typedef _Float16 half8 __attribute__((ext_vector_type(8)));
typedef __attribute__((ext_vector_type(16))) float    f32x16;
typedef __attribute__((ext_vector_type(4)))  float    float4v;

union BFU { __hip_bfloat16 b; unsigned short u; };
__device__ __forceinline__ unsigned short f2bf(float x) { BFU u; u.b = __float2bfloat16(x); return u.u; }

// full drain (vmcnt=0, expcnt=0, lgkmcnt=0) — guarantees LDS-buffer reuse safety
__device__ __forceinline__ void full_drain_barrier() {
    __builtin_amdgcn_s_waitcnt(0);
    __syncthreads();
}

// ---------------- pre-pass: K -> fp16 (RNE), V -> Vt (bf16 transpose, key bit2<->3 swap) ----
__global__ void prep(const float* __restrict__ K, const float* __restrict__ V,
                     _Float16* __restrict__ Kh, unsigned short* __restrict__ Vt) {
    __shared__ __attribute__((aligned(16))) unsigned short tile[64 * 72];
    int b = blockIdx.x;
    int t = threadIdx.x;
    if (b < 512) {                        // K fp16: 1M elements, 8 per thread
        int idx = (b * 256 + t) * 8;
        float4v x0 = *(const float4v*)(K + idx);
        float4v x1 = *(const float4v*)(K + idx + 4);
        half8 o;
#pragma unroll
        for (int j = 0; j < 4; ++j) { o[j] = (_Float16)x0[j]; o[4 + j] = (_Float16)x1[j]; }
        *(half8*)(Kh + idx) = o;
    } else {                              // V transpose: 64(m) x 64(n) tiles
        int tv = b - 512;
        int m0 = (tv >> 1) * 64, n0 = (tv & 1) * 64;
#pragma unroll
        for (int it = 0; it < 4; ++it) {
            int id = t + it * 256;
            int mm = id >> 4, nn0 = (id & 15) * 4;
            // rho: swap bits 2 and 3 of the key index (involution, within-16)
            int mmP = (mm & ~12) | ((mm & 4) << 1) | ((mm & 8) >> 1);
            float4v x = *(const float4v*)(V + (size_t)(m0 + mm) * DH + n0 + nn0);
#pragma unroll
            for (int j = 0; j < 4; ++j)
                tile[(nn0 + j) * 72 + mmP] = f2bf(x[j]);
        }
        __syncthreads();
        int nn = t >> 2, ch = t & 3;
        *(short8*)(Vt + (size_t)(n0 + nn) * NKEY + m0 + ch * 16)     = *(const short8*)&tile[nn * 72 + ch * 16];
        *(short8*)(Vt + (size_t)(n0 + nn) * NKEY + m0 + ch * 16 + 8) = *(const short8*)&tile[nn * 72 + ch * 16 + 8];
    }
}

// ------- forward: S^T = K*(Q*log2e)^T fp16, p = 2^S (no max), O^T = Vtp*P^T bf16 -------
__launch_bounds__(512, 2)
__global__ void attn_fwd(const float* __restrict__ Q,
                         const _Float16* __restrict__ Kh,
                         const unsigned short* __restrict__ Vt,
                         unsigned short* __restrict__ Opart, float* __restrict__ lpart,
                         int KS) {
    __shared__ __attribute__((aligned(16))) char sbuf[2 * BUFB];

    const int tid  = threadIdx.x;
    const int lane = tid & 63;
    const int w    = tid >> 6;            // 0..7
    const int l31  = lane & 31;
    const int h    = lane >> 5;

    const int s  = blockIdx.x % KS;
    const int qb = blockIdx.x / KS;
    const int mlen   = NKEY / KS;
    const int kbase  = s * mlen;
    const int ntiles = mlen / BK;          // 8 at KS=16 (even)

    // ---- staging: 2048 chunks of 16B per tile, 4 global_load_lds per wave
    //      (waves 0-3 stage the K tile, waves 4-7 the V tile)
    const char* gbase[4]; int mult[4]; int ldsoff[4];
#pragma unroll
    for (int i = 0; i < 4; ++i) {
        int Lb = w * 256 + i * 64;
        int L  = Lb + lane;
        const char* gb; int mu;
        if (Lb < 1024) { int r = L >> 4, cg = (L & 15) ^ (r & 15);
                         gb = (const char*)Kh + r * 256 + cg * 16; mu = 256; }
        else           { int Lv = L - 1024; int n = Lv >> 3, cg = (Lv & 7) ^ (n & 7);
                         gb = (const char*)Vt + (size_t)n * (NKEY * 2) + cg * 16; mu = 2; }
        gbase[i] = gb; mult[i] = mu; ldsoff[i] = Lb * 16;
    }

    // ---- Q fragments fp16, scaled by log2e; B-layout: lane=query, k=c*16+h*8+j
    const int qrow = qb * BQ + w * 32 + l31;
    half8 qf[8];
#pragma unroll
    for (int c = 0; c < 8; ++c) {
        const float* qp = Q + (size_t)qrow * DH + c * 16 + h * 8;
        float4v x0 = *(const float4v*)qp;
        float4v x1 = *(const float4v*)(qp + 4);
#pragma unroll
        for (int i = 0; i < 4; ++i) {
            qf[c][i]     = (_Float16)(x0[i] * LOG2E);
            qf[c][4 + i] = (_Float16)(x1[i] * LOG2E);
        }
    }

    // ---- LDS read offsets (bytes within one buffer)
    int koff[8];
#pragma unroll
    for (int c = 0; c < 8; ++c)
        koff[c] = l31 * 256 + (((c * 2 + h) ^ (l31 & 15)) << 4);
    int voff[4];
#pragma unroll
    for (int c2 = 0; c2 < 4; ++c2)
        voff[c2] = 16384 + l31 * 128 + (((c2 * 2 + h) ^ (l31 & 7)) << 4);

    float lsum = 0.0f;   // per-half-wave partial; combined once in epilogue
    f32x16 O[4];
#pragma unroll
    for (int ct = 0; ct < 4; ++ct)
#pragma unroll
        for (int r = 0; r < 16; ++r) O[ct][r] = 0.0f;

    auto stage = [&](int t, int bufbyte) {       // t = local tile index
        int kb = kbase + t * BK;
#pragma unroll
        for (int i = 0; i < 4; ++i) {
            const char* g = gbase[i] + (size_t)kb * mult[i];
            __builtin_amdgcn_global_load_lds(
                (const __attribute__((address_space(1))) unsigned int*)g,
                (__attribute__((address_space(3))) unsigned int*)(sbuf + bufbyte + ldsoff[i]),
                16, 0, 0);
        }
    };

    auto compute_tile = [&](int BUF) {
        const char* bp = sbuf + BUF;
        // S^T = K * Q^T (fp16): two 32-key groups (independent MFMA chains)
        f32x16 S0, S1;
#pragma unroll
        for (int r = 0; r < 16; ++r) { S0[r] = 0.0f; S1[r] = 0.0f; }
#pragma unroll
        for (int c = 0; c < 8; ++c) {
            half8 k0 = *(const half8*)(bp + koff[c]);
            half8 k1 = *(const half8*)(bp + koff[c] + 8192);
            S0 = __builtin_amdgcn_mfma_f32_32x32x16_f16(k0, qf[c], S0, 0, 0, 0);
            S1 = __builtin_amdgcn_mfma_f32_32x32x16_f16(k1, qf[c], S1, 0, 0, 0);
        }
        union PU { unsigned int u[4]; short8 s8; } B0, B1, B2, B3;
        // ---- group 0: hoist V reads -> exp2(S0) covers their ~120cyc latency -> pack -> PV
        {
            short8 va0[4], va1[4];
#pragma unroll
            for (int ct = 0; ct < 4; ++ct) {
                va0[ct] = *(const short8*)(bp + voff[0] + ct * 4096);
                va1[ct] = *(const short8*)(bp + voff[1] + ct * 4096);
            }
            float p0[16]; float ps = 0.0f;
#pragma unroll
            for (int r = 0; r < 16; ++r) { p0[r] = __builtin_amdgcn_exp2f(S0[r]); ps += p0[r]; }
            lsum += ps;                 // shfl deferred to epilogue
#pragma unroll
            for (int j = 0; j < 4; ++j) {
                B0.u[j] = __builtin_amdgcn_perm(__float_as_uint(p0[2*j+1]), __float_as_uint(p0[2*j]),   0x07060302u);
                B1.u[j] = __builtin_amdgcn_perm(__float_as_uint(p0[2*j+9]), __float_as_uint(p0[2*j+8]), 0x07060302u);
            }
#pragma unroll
            for (int ct = 0; ct < 4; ++ct) {
                O[ct] = __builtin_amdgcn_mfma_f32_32x32x16_bf16(va0[ct], B0.s8, O[ct], 0, 0, 0);
                O[ct] = __builtin_amdgcn_mfma_f32_32x32x16_bf16(va1[ct], B1.s8, O[ct], 0, 0, 0);
            }
        }
        // ---- group 1: hoist V reads -> exp2(S1) covers latency (overlaps group-0 PV too)
        {
            short8 va2[4], va3[4];
#pragma unroll
            for (int ct = 0; ct < 4; ++ct) {
                va2[ct] = *(const short8*)(bp + voff[2] + ct * 4096);
                va3[ct] = *(const short8*)(bp + voff[3] + ct * 4096);
            }
            float p1[16]; float ps = 0.0f;
#pragma unroll
            for (int r = 0; r < 16; ++r) { p1[r] = __builtin_amdgcn_exp2f(S1[r]); ps += p1[r]; }
            lsum += ps;
#pragma unroll
            for (int j = 0; j < 4; ++j) {
                B2.u[j] = __builtin_amdgcn_perm(__float_as_uint(p1[2*j+1]), __float_as_uint(p1[2*j]),   0x07060302u);
                B3.u[j] = __builtin_amdgcn_perm(__float_as_uint(p1[2*j+9]), __float_as_uint(p1[2*j+8]), 0x07060302u);
            }
#pragma unroll
            for (int ct = 0; ct < 4; ++ct) {
                O[ct] = __builtin_amdgcn_mfma_f32_32x32x16_bf16(va2[ct], B2.s8, O[ct], 0, 0, 0);
                O[ct] = __builtin_amdgcn_mfma_f32_32x32x16_bf16(va3[ct], B3.s8, O[ct], 0, 0, 0);
            }
        }
    };

    // ---- double-buffered main loop (ntiles even); full drain before each barrier
    stage(0, 0);
    for (int t = 0; t < ntiles; t += 2) {
        full_drain_barrier();                  // buf0 staged; all buf1 readers done
        stage(t + 1, BUFB);
        compute_tile(0);
        full_drain_barrier();                  // buf1 staged; all buf0 readers done
        if (t + 2 < ntiles) stage(t + 2, 0);
        compute_tile(BUFB);
    }

    // ---- epilogue: combine half-wave lsums, then store O^T C-layout
    lsum += __shfl_xor(lsum, 32, 64);
    {
        unsigned short* Ob = Opart + ((size_t)s * NQ + qrow) * DH;
#pragma unroll
        for (int ct = 0; ct < 4; ++ct)
#pragma unroll
            for (int g = 0; g < 4; ++g) {
                short4v v;
#pragma unroll
                for (int j = 0; j < 4; ++j) v[j] = (short)f2bf(O[ct][4 * g + j]);
                *(short4v*)(Ob + ct * 32 + 8 * g + 4 * h) = v;
            }
        if (h == 0)
            lpart[(size_t)s * NQ + qrow] = lsum;
    }
}

__global__ void attn_combine(const unsigned short* __restrict__ Opart,
                             const float* __restrict__ lpart, float* __restrict__ out, int KS) {
    int idx = blockIdx.x * 256 + threadIdx.x;   // one thread per 4 output cols
    int row = idx >> 5;
    int col = (idx & 31) << 2;
    float den = 0.0f;
    float a0 = 0.0f, a1 = 0.0f, a2 = 0.0f, a3 = 0.0f;
    for (int s2 = 0; s2 < KS; ++s2) {
        den += lpart[(size_t)s2 * NQ + row];
        const unsigned short* op = Opart + ((size_t)s2 * NQ + row) * DH + col;
        uint2 u = *(const uint2*)op;
        a0 += __uint_as_float(u.x << 16);
        a1 += __uint_as_float(u.x & 0xffff0000u);
        a2 += __uint_as_float(u.y << 16);
        a3 += __uint_as_float(u.y & 0xffff0000u);
    }
    float r = 1.0f / den;
    float4v v; v[0] = a0 * r; v[1] = a1 * r; v[2] = a2 * r; v[3] = a3 * r;
    *(float4v*)(out + (size_t)row * DH + col) = v;
}

extern "C" void kernel_launch(void* const* d_in, const int* in_sizes, int n_in,
                              void* d_out, int out_size, void* d_ws, size_t ws_size,
                              hipStream_t stream) {
    const float* Q = (const float*)d_in[0];
    const float* K = (const float*)d_in[1];
    const float* V = (const float*)d_in[2];
    float* out = (float*)d_out;

    const size_t prep_bytes = 2 * (size_t)NKEY * DH * sizeof(unsigned short); // 4 MB
    int KS = 16;   // grid = 32*16 = 512 blocks -> exactly 2 blocks/CU, 16 waves/CU
    while (KS > 1 &&
           ws_size < prep_bytes + (size_t)KS * ((size_t)NQ * DH * 2 + NQ * 4))
        KS >>= 1;

    _Float16* Kh = (_Float16*)d_ws;
    unsigned short* Vt = (unsigned short*)(Kh + (size_t)NKEY * DH);
    unsigned short* Opart = Vt + (size_t)NKEY * DH;
    float* lpart = (float*)(Opart + (size_t)KS * NQ * DH);

    hipLaunchKernelGGL(prep, dim3(768), dim3(256), 0, stream, K, V, Kh, Vt);
    hipLaunchKernelGGL(attn_fwd, dim3((NQ / BQ) * KS), dim3(512), 0, stream,
                       Q, Kh, Vt, Opart, lpart, KS);
    hipLaunchKernelGGL(attn_combine, dim3((NQ * DH) / 4 / 256), dim3(256), 0, stream,
                       Opart, lpart, out, KS);
}